// Round 1
// baseline (625.843 us; speedup 1.0000x reference)
//
#include <hip/hip_runtime.h>

#define D 64
#define IN 128
#define NEG_SLOPE 0.01f

// ---- monotone float<->uint key for atomicMax on floats ----
__device__ __forceinline__ unsigned fkey(float f) {
    unsigned b = __float_as_uint(f);
    return (b & 0x80000000u) ? ~b : (b | 0x80000000u);
}
__device__ __forceinline__ float funkey(unsigned k) {
    unsigned b = (k & 0x80000000u) ? (k ^ 0x80000000u) : ~k;
    return __uint_as_float(b);
}

// Kernel 1: z = h @ fc_w^T  (N x 64), fused a_src = z.attn_w[:64], a_dst = z.attn_w[64:]
// one wave per node; lane = output dim d
__global__ __launch_bounds__(256) void k_project(
    const float* __restrict__ h, const float* __restrict__ fc_w,
    const float* __restrict__ attn_w,
    float* __restrict__ z, float* __restrict__ a_src, float* __restrict__ a_dst,
    int n_nodes)
{
    __shared__ float w_lds[D][IN + 1];   // +1 pad: lanes differ in d -> 2 lanes/bank (free)
    __shared__ float h_lds[4][IN];

    const int tid = threadIdx.x;
    // stage fc_w (64x128 = 8192 floats) cooperatively
    for (int i = tid; i < D * IN; i += 256) {
        w_lds[i / IN][i % IN] = fc_w[i];
    }
    const int wave = tid >> 6;
    const int lane = tid & 63;
    const int node = blockIdx.x * 4 + wave;
    if (node < n_nodes) {
        h_lds[wave][lane]      = h[(size_t)node * IN + lane];
        h_lds[wave][lane + 64] = h[(size_t)node * IN + lane + 64];
    }
    __syncthreads();
    if (node >= n_nodes) return;

    float acc = 0.f;
    #pragma unroll
    for (int k = 0; k < IN; ++k)
        acc = fmaf(h_lds[wave][k], w_lds[lane][k], acc);

    z[(size_t)node * D + lane] = acc;

    float as = acc * attn_w[lane];
    float ad = acc * attn_w[D + lane];
    #pragma unroll
    for (int off = 32; off > 0; off >>= 1) {
        as += __shfl_xor(as, off, 64);
        ad += __shfl_xor(ad, off, 64);
    }
    if (lane == 0) { a_src[node] = as; a_dst[node] = ad; }
}

// Kernel 2: e = leaky_relu(a_src[src] + a_dst[dst]); segment max over dst via uint-key atomicMax
__global__ __launch_bounds__(256) void k_edge_max(
    const int* __restrict__ src, const int* __restrict__ dst,
    const float* __restrict__ a_src, const float* __restrict__ a_dst,
    float* __restrict__ e_edge, unsigned* __restrict__ emax_key, int n_edges)
{
    int i = blockIdx.x * 256 + threadIdx.x;
    if (i >= n_edges) return;
    int s = src[i], t = dst[i];
    float e = a_src[s] + a_dst[t];
    e = (e >= 0.f) ? e : NEG_SLOPE * e;
    e_edge[i] = e;
    atomicMax(&emax_key[t], fkey(e));
}

// Kernel 3: ex = exp(e - max[dst]); denom[dst] += ex  (ex stored in place over e_edge)
__global__ __launch_bounds__(256) void k_edge_exp(
    const int* __restrict__ dst,
    float* __restrict__ e_edge, const unsigned* __restrict__ emax_key,
    float* __restrict__ denom, int n_edges)
{
    int i = blockIdx.x * 256 + threadIdx.x;
    if (i >= n_edges) return;
    int t = dst[i];
    float m = funkey(emax_key[t]);
    float ex = expf(e_edge[i] - m);
    e_edge[i] = ex;
    atomicAdd(&denom[t], ex);
}

// Kernel 4: out[dst] += (ex/denom[dst]) * z[src]  — one wave per edge, lane = dim
__global__ __launch_bounds__(256) void k_scatter(
    const int* __restrict__ src, const int* __restrict__ dst,
    const float* __restrict__ ex_edge, const float* __restrict__ denom,
    const float* __restrict__ z, float* __restrict__ out, int n_edges)
{
    int e = blockIdx.x * 4 + (threadIdx.x >> 6);
    if (e >= n_edges) return;
    int lane = threadIdx.x & 63;
    int s = src[e], t = dst[e];
    float alpha = ex_edge[e] / denom[t];
    atomicAdd(&out[(size_t)t * D + lane], alpha * z[(size_t)s * D + lane]);
}

extern "C" void kernel_launch(void* const* d_in, const int* in_sizes, int n_in,
                              void* d_out, int out_size, void* d_ws, size_t ws_size,
                              hipStream_t stream) {
    const float* h      = (const float*)d_in[0];
    const int*   src    = (const int*)d_in[1];
    const int*   dst    = (const int*)d_in[2];
    const float* fc_w   = (const float*)d_in[3];
    const float* attn_w = (const float*)d_in[4];

    const int n_nodes = in_sizes[0] / IN;
    const int n_edges = in_sizes[1];
    float* out = (float*)d_out;

    // workspace layout
    char* p = (char*)d_ws;
    float*    z      = (float*)p;    p += (size_t)n_nodes * D * sizeof(float);
    float*    a_src  = (float*)p;    p += (size_t)n_nodes * sizeof(float);
    float*    a_dst  = (float*)p;    p += (size_t)n_nodes * sizeof(float);
    unsigned* emax   = (unsigned*)p; p += (size_t)n_nodes * sizeof(unsigned);
    float*    denom  = (float*)p;    p += (size_t)n_nodes * sizeof(float);
    float*    e_edge = (float*)p;    p += (size_t)n_edges * sizeof(float);

    // zero accumulators every call (graph replays don't re-poison)
    hipMemsetAsync(out,   0, (size_t)n_nodes * D * sizeof(float), stream);
    hipMemsetAsync(emax,  0, (size_t)n_nodes * sizeof(unsigned),  stream);
    hipMemsetAsync(denom, 0, (size_t)n_nodes * sizeof(float),     stream);

    k_project<<<dim3((n_nodes + 3) / 4), dim3(256), 0, stream>>>(
        h, fc_w, attn_w, z, a_src, a_dst, n_nodes);
    k_edge_max<<<dim3((n_edges + 255) / 256), dim3(256), 0, stream>>>(
        src, dst, a_src, a_dst, e_edge, emax, n_edges);
    k_edge_exp<<<dim3((n_edges + 255) / 256), dim3(256), 0, stream>>>(
        dst, e_edge, emax, denom, n_edges);
    k_scatter<<<dim3((n_edges + 3) / 4), dim3(256), 0, stream>>>(
        src, dst, e_edge, denom, z, out, n_edges);
}